// Round 4
// baseline (808.728 us; speedup 1.0000x reference)
//
#include <hip/hip_runtime.h>

#define BB   4
#define NN   16384
#define KK   32
#define HID  128
#define OUTF 64

typedef _Float16 f16x8 __attribute__((ext_vector_type(8)));
typedef _Float16 f16x4 __attribute__((ext_vector_type(4)));
typedef float    f32x4 __attribute__((ext_vector_type(4)));

// ---------------------------------------------------------------------------
// prep1: wc = pe_w2 @ W1b (64x128), b1c = mlp_b1 + pe_b2 @ W1b. (verified R1)
// ---------------------------------------------------------------------------
__global__ __launch_bounds__(256) void prep1_kernel(
    const float* __restrict__ pe_w2, const float* __restrict__ pe_b2,
    const float* __restrict__ mlp_w1, const float* __restrict__ mlp_b1,
    float* __restrict__ wc, float* __restrict__ b1c)
{
    __shared__ float s_w2[64 * 64];
    __shared__ float s_b2[64];
    int t = threadIdx.x;
    for (int i = t; i < 64 * 64; i += 256) s_w2[i] = pe_w2[i];
    if (t < 64) s_b2[t] = pe_b2[t];
    __syncthreads();

    int j = t & 127, half = t >> 7;
    float col[64];
#pragma unroll
    for (int c = 0; c < 64; ++c) col[c] = mlp_w1[(32 + c) * HID + j];

    if (half == 0) {
        float bacc = mlp_b1[j];
#pragma unroll 16
        for (int c = 0; c < 64; ++c) bacc = fmaf(s_b2[c], col[c], bacc);
        b1c[j] = bacc;
    }
    for (int i = half * 32; i < half * 32 + 32; ++i) {
        float a = 0.f;
#pragma unroll 16
        for (int c = 0; c < 64; ++c) a = fmaf(s_w2[i * 64 + c], col[c], a);
        wc[i * HID + j] = a;
    }
}

// ---------------------------------------------------------------------------
// prep2: pack fp16 B-fragments (MFMA 16x16x32 B-layout). (verified R2/R3)
// ---------------------------------------------------------------------------
__global__ __launch_bounds__(256) void prep2_kernel(
    const float* __restrict__ mlp_w1, const float* __restrict__ wc,
    const float* __restrict__ mlp_w2,
    _Float16* __restrict__ gB1, _Float16* __restrict__ gW2)
{
    int t = blockIdx.x * 256 + threadIdx.x;
    if (t < 24 * 512) {
        int tile = t >> 9, rem = t & 511, l = rem >> 3, j = rem & 7;
        int ks = tile >> 3, nt = tile & 7, q = l >> 4;
        int k = ks * 32 + q * 8 + j, n = nt * 16 + (l & 15);
        float v = (k < 32) ? mlp_w1[k * HID + n] : wc[(k - 32) * HID + n];
        gB1[t] = (_Float16)v;
    } else {
        int t2 = t - 24 * 512;
        int tile = t2 >> 9, rem = t2 & 511, l = rem >> 3, j = rem & 7;
        int ks = tile >> 2, nt = tile & 3, q = l >> 4;
        int k = ks * 32 + q * 8 + j, n = nt * 16 + (l & 15);
        gW2[t2] = (_Float16)mlp_w2[k * OUTF + n];
    }
}

// ---------------------------------------------------------------------------
// prepF: features fp32 -> fp16 rows (64 B each); points -> padded float4.
// ---------------------------------------------------------------------------
__global__ __launch_bounds__(256) void prepF_kernel(
    const float* __restrict__ features, const float* __restrict__ points,
    _Float16* __restrict__ feat16, float4* __restrict__ pts4)
{
    int t = blockIdx.x * 256 + threadIdx.x;
    if (t < BB * NN * 8) {                       // 524288 float4 of features
        float4 v = ((const float4*)features)[t];
        f16x4 h;
        h[0] = (_Float16)v.x; h[1] = (_Float16)v.y;
        h[2] = (_Float16)v.z; h[3] = (_Float16)v.w;
        *(f16x4*)(feat16 + (size_t)t * 4) = h;
    } else {
        int i = t - BB * NN * 8;
        if (i < BB * NN) {
            const float* p = points + (size_t)i * 3;
            pts4[i] = make_float4(p[0], p[1], p[2], 0.f);
        }
    }
}

// ---------------------------------------------------------------------------
// Main: 1024 blocks x 4 waves; one wave = 16 consecutive points.
// Register-lean: pe tables in LDS (broadcast), A-frags gathered directly
// from fp16 global (MFMA layout), W2 frags streamed from global in epilogue.
// LDS = 45.5 KB -> 3 blocks/CU (12 waves/CU).
// ---------------------------------------------------------------------------
__global__ __launch_bounds__(256, 3) void DensityAwareFeatureAggregator_main(
    const float4* __restrict__ pts4,      // (B*N) padded
    const _Float16* __restrict__ feat16,  // (B*N,32) f16
    const int*   __restrict__ nbr,        // (B,N,32)
    const float* __restrict__ pe_w1,      // (3,64)
    const float* __restrict__ pe_b1,      // (64)
    const float* __restrict__ b1c,        // (128) fused bias
    const _Float16* __restrict__ gB1,     // W1c frags (24 tiles)
    const _Float16* __restrict__ gW2,     // W2 frags (16 tiles)
    const float* __restrict__ b2g,        // (64)
    float* __restrict__ out)              // (B,N,64)
{
    __shared__ __align__(16) _Float16 sB1[24 * 512];     // 24576 B
    __shared__ __align__(16) float4   sTab[64];          //  1024 B
    __shared__ __align__(16) float4   sR[4][32];         //  2048 B
    __shared__ int                    sI[4][32];         //   512 B
    __shared__ __align__(16) _Float16 sHM[4][16 * 136];  // 17408 B
    // total 45568 B -> 3 blocks/CU

    const int t = threadIdx.x;
    {
        const uint4* g = (const uint4*)gB1;
        uint4* d = (uint4*)sB1;
        for (int i = t; i < 1536; i += 256) d[i] = g[i];
        if (t < 64)
            sTab[t] = make_float4(pe_w1[t], pe_w1[64 + t], pe_w1[128 + t], pe_b1[t]);
    }
    __syncthreads();

    const int w = t >> 6, l = t & 63, q = l >> 4, c16 = l & 15;
    const int nb   = (blockIdx.x & 7) * 128 + (blockIdx.x >> 3);
    const int base = (nb * 4 + w) * 16;

    float bias1[8];
#pragma unroll
    for (int nt = 0; nt < 8; ++nt) bias1[nt] = b1c[nt * 16 + c16];

    const f16x8* B1f = (const f16x8*)sB1;
    _Float16* hmw = &sHM[w][0];

#pragma unroll 1
    for (int p = 0; p < 16; ++p) {
        const int m = base + p;
        const int b = m >> 14;
        const int n = m & (NN - 1);
        const int bo = b << 14;

        if (l < KK) {
            int idx = nbr[(size_t)m * KK + l];
            sI[w][l] = idx;
            float4 pc = pts4[bo + n];
            float4 pn = pts4[bo + idx];
            sR[w][l] = make_float4(pn.x - pc.x, pn.y - pc.y, pn.z - pc.z, 0.f);
        }

        // feature A-frags straight from global fp16 (MFMA A layout)
        int i0 = sI[w][c16];
        int i1 = sI[w][16 + c16];
        f16x8 af0 = ((const f16x8*)(feat16 + ((size_t)(bo + i0)) * 32))[q];
        f16x8 af1 = ((const f16x8*)(feat16 + ((size_t)(bo + i1)) * 32))[q];

        // pe A-frags: tables broadcast from LDS (no VGPR arrays)
        float4 r0 = sR[w][c16];
        float4 r1 = sR[w][16 + c16];
        f16x8 ap10, ap20, ap11, ap21;
#pragma unroll
        for (int j = 0; j < 8; ++j) {
            float4 ta = sTab[q * 8 + j];
            float4 tb = sTab[32 + q * 8 + j];
            float v;
            v = fmaf(r0.x, ta.x, fmaf(r0.y, ta.y, fmaf(r0.z, ta.z, ta.w)));
            ap10[j] = (_Float16)fmaxf(v, 0.f);
            v = fmaf(r0.x, tb.x, fmaf(r0.y, tb.y, fmaf(r0.z, tb.z, tb.w)));
            ap20[j] = (_Float16)fmaxf(v, 0.f);
            v = fmaf(r1.x, ta.x, fmaf(r1.y, ta.y, fmaf(r1.z, ta.z, ta.w)));
            ap11[j] = (_Float16)fmaxf(v, 0.f);
            v = fmaf(r1.x, tb.x, fmaf(r1.y, tb.y, fmaf(r1.z, tb.z, tb.w)));
            ap21[j] = (_Float16)fmaxf(v, 0.f);
        }

        // MFMA main: 3 K-steps x 8 N-tiles x 2 M-tiles (layout verified R2/R3)
        f32x4 acc[2][8];
#pragma unroll
        for (int nt = 0; nt < 8; ++nt) {
            f32x4 z; z[0] = z[1] = z[2] = z[3] = bias1[nt];
            acc[0][nt] = z; acc[1][nt] = z;
        }
#pragma unroll
        for (int nt = 0; nt < 8; ++nt) {
            f16x8 bf = B1f[nt * 64 + l];
            acc[0][nt] = __builtin_amdgcn_mfma_f32_16x16x32_f16(af0, bf, acc[0][nt], 0, 0, 0);
            acc[1][nt] = __builtin_amdgcn_mfma_f32_16x16x32_f16(af1, bf, acc[1][nt], 0, 0, 0);
        }
#pragma unroll
        for (int nt = 0; nt < 8; ++nt) {
            f16x8 bf = B1f[(8 + nt) * 64 + l];
            acc[0][nt] = __builtin_amdgcn_mfma_f32_16x16x32_f16(ap10, bf, acc[0][nt], 0, 0, 0);
            acc[1][nt] = __builtin_amdgcn_mfma_f32_16x16x32_f16(ap11, bf, acc[1][nt], 0, 0, 0);
        }
#pragma unroll
        for (int nt = 0; nt < 8; ++nt) {
            f16x8 bf = B1f[(16 + nt) * 64 + l];
            acc[0][nt] = __builtin_amdgcn_mfma_f32_16x16x32_f16(ap20, bf, acc[0][nt], 0, 0, 0);
            acc[1][nt] = __builtin_amdgcn_mfma_f32_16x16x32_f16(ap21, bf, acc[1][nt], 0, 0, 0);
        }

        // relu + mean over 32 neighbors -> hm row p
#pragma unroll
        for (int nt = 0; nt < 8; ++nt) {
            float s = fmaxf(acc[0][nt][0], 0.f) + fmaxf(acc[0][nt][1], 0.f)
                    + fmaxf(acc[0][nt][2], 0.f) + fmaxf(acc[0][nt][3], 0.f)
                    + fmaxf(acc[1][nt][0], 0.f) + fmaxf(acc[1][nt][1], 0.f)
                    + fmaxf(acc[1][nt][2], 0.f) + fmaxf(acc[1][nt][3], 0.f);
            s += __shfl_xor(s, 16, 64);
            s += __shfl_xor(s, 32, 64);
            if (q == 0) hmw[p * 136 + nt * 16 + c16] = (_Float16)(s * 0.03125f);
        }
    }

    // epilogue: OUT(16x64) = HM(16x128) @ W2 + b2  (W2 frags from global)
    const f16x8* W2f = (const f16x8*)gW2;
    f32x4 acc2[4];
#pragma unroll
    for (int nt = 0; nt < 4; ++nt) {
        f32x4 z; float bv = b2g[nt * 16 + c16];
        z[0] = z[1] = z[2] = z[3] = bv;
        acc2[nt] = z;
    }
#pragma unroll
    for (int ks = 0; ks < 4; ++ks) {
        f16x8 a2 = *(const f16x8*)&hmw[c16 * 136 + ks * 32 + q * 8];
#pragma unroll
        for (int nt = 0; nt < 4; ++nt) {
            f16x8 bf = W2f[(ks * 4 + nt) * 64 + l];
            acc2[nt] = __builtin_amdgcn_mfma_f32_16x16x32_f16(a2, bf, acc2[nt], 0, 0, 0);
        }
    }
#pragma unroll
    for (int nt = 0; nt < 4; ++nt)
#pragma unroll
        for (int r = 0; r < 4; ++r)
            out[(size_t)(base + q * 4 + r) * OUTF + nt * 16 + c16] = acc2[nt][r];
}

// ---------------------------------------------------------------------------
extern "C" void kernel_launch(void* const* d_in, const int* in_sizes, int n_in,
                              void* d_out, int out_size, void* d_ws, size_t ws_size,
                              hipStream_t stream)
{
    const float* points   = (const float*)d_in[0];
    const float* features = (const float*)d_in[1];
    // d_in[2] density: provably unused (softmax over K identical values = 1/K)
    const int*   nbr      = (const int*)d_in[3];
    const float* pe_w1    = (const float*)d_in[4];
    const float* pe_b1    = (const float*)d_in[5];
    const float* pe_w2    = (const float*)d_in[6];
    const float* pe_b2    = (const float*)d_in[7];
    const float* mlp_w1   = (const float*)d_in[8];
    const float* mlp_b1   = (const float*)d_in[9];
    const float* mlp_w2   = (const float*)d_in[10];
    const float* mlp_b2   = (const float*)d_in[11];

    float* wsf = (float*)d_ws;
    float*    wc     = wsf;                         // 8192 f32
    float*    b1c    = wsf + 8192;                  // 128 f32
    _Float16* gB1    = (_Float16*)(wsf + 8320);     // 12288 f16 (6144 f32 slots)
    _Float16* gW2    = (_Float16*)(wsf + 14464);    // 8192 f16  (4096 f32 slots)
    float4*   pts4   = (float4*)(wsf + 18560);      // 65536 float4 (262144 f32)
    _Float16* feat16 = (_Float16*)(wsf + 280704);   // 2097152 f16 (1048576 f32)

    prep1_kernel<<<1, 256, 0, stream>>>(pe_w2, pe_b2, mlp_w1, mlp_b1, wc, b1c);
    prep2_kernel<<<80, 256, 0, stream>>>(mlp_w1, wc, mlp_w2, gB1, gW2);
    prepF_kernel<<<2304, 256, 0, stream>>>(features, points, feat16, pts4);

    DensityAwareFeatureAggregator_main<<<1024, 256, 0, stream>>>(
        pts4, feat16, nbr, pe_w1, pe_b1, b1c, gB1, gW2, mlp_b2,
        (float*)d_out);
}

// Round 5
// 255.806 us; speedup vs baseline: 3.1615x; 3.1615x over previous
//
#include <hip/hip_runtime.h>

#define BB   4
#define NN   16384
#define KK   32
#define HID  128
#define OUTF 64

typedef _Float16 f16x8 __attribute__((ext_vector_type(8)));
typedef _Float16 f16x4 __attribute__((ext_vector_type(4)));
typedef float    f32x4 __attribute__((ext_vector_type(4)));

// ---------------------------------------------------------------------------
// prep1: wc = pe_w2 @ W1b (64x128), b1c = mlp_b1 + pe_b2 @ W1b. (verified R1)
// ---------------------------------------------------------------------------
__global__ __launch_bounds__(256) void prep1_kernel(
    const float* __restrict__ pe_w2, const float* __restrict__ pe_b2,
    const float* __restrict__ mlp_w1, const float* __restrict__ mlp_b1,
    float* __restrict__ wc, float* __restrict__ b1c)
{
    __shared__ float s_w2[64 * 64];
    __shared__ float s_b2[64];
    int t = threadIdx.x;
    for (int i = t; i < 64 * 64; i += 256) s_w2[i] = pe_w2[i];
    if (t < 64) s_b2[t] = pe_b2[t];
    __syncthreads();

    int j = t & 127, half = t >> 7;
    float col[64];
#pragma unroll
    for (int c = 0; c < 64; ++c) col[c] = mlp_w1[(32 + c) * HID + j];

    if (half == 0) {
        float bacc = mlp_b1[j];
#pragma unroll 16
        for (int c = 0; c < 64; ++c) bacc = fmaf(s_b2[c], col[c], bacc);
        b1c[j] = bacc;
    }
    for (int i = half * 32; i < half * 32 + 32; ++i) {
        float a = 0.f;
#pragma unroll 16
        for (int c = 0; c < 64; ++c) a = fmaf(s_w2[i * 64 + c], col[c], a);
        wc[i * HID + j] = a;
    }
}

// ---------------------------------------------------------------------------
// prep2: pack fp16 B-fragments (MFMA 16x16x32 B-layout). (verified R2/R3)
// ---------------------------------------------------------------------------
__global__ __launch_bounds__(256) void prep2_kernel(
    const float* __restrict__ mlp_w1, const float* __restrict__ wc,
    const float* __restrict__ mlp_w2,
    _Float16* __restrict__ gB1, _Float16* __restrict__ gW2)
{
    int t = blockIdx.x * 256 + threadIdx.x;
    if (t < 24 * 512) {
        int tile = t >> 9, rem = t & 511, l = rem >> 3, j = rem & 7;
        int ks = tile >> 3, nt = tile & 7, q = l >> 4;
        int k = ks * 32 + q * 8 + j, n = nt * 16 + (l & 15);
        float v = (k < 32) ? mlp_w1[k * HID + n] : wc[(k - 32) * HID + n];
        gB1[t] = (_Float16)v;
    } else {
        int t2 = t - 24 * 512;
        int tile = t2 >> 9, rem = t2 & 511, l = rem >> 3, j = rem & 7;
        int ks = tile >> 2, nt = tile & 3, q = l >> 4;
        int k = ks * 32 + q * 8 + j, n = nt * 16 + (l & 15);
        gW2[t2] = (_Float16)mlp_w2[k * OUTF + n];
    }
}

// ---------------------------------------------------------------------------
// prepF: features fp32 -> fp16 rows (64 B each); points -> padded float4.
// fp16 table = 1 MB/batch -> L2-resident under the XCD-contiguous schedule.
// ---------------------------------------------------------------------------
__global__ __launch_bounds__(256) void prepF_kernel(
    const float* __restrict__ features, const float* __restrict__ points,
    _Float16* __restrict__ feat16, float4* __restrict__ pts4)
{
    int t = blockIdx.x * 256 + threadIdx.x;
    if (t < BB * NN * 8) {                       // 524288 float4 of features
        float4 v = ((const float4*)features)[t];
        f16x4 h;
        h[0] = (_Float16)v.x; h[1] = (_Float16)v.y;
        h[2] = (_Float16)v.z; h[3] = (_Float16)v.w;
        *(f16x4*)(feat16 + (size_t)t * 4) = h;
    } else {
        int i = t - BB * NN * 8;
        if (i < BB * NN) {
            const float* p = points + (size_t)i * 3;
            pts4[i] = make_float4(p[0], p[1], p[2], 0.f);
        }
    }
}

// ---------------------------------------------------------------------------
// Main: 1024 blocks x 4 waves; one wave = 16 consecutive points.
// KEY CHANGE vs R4: per-N-tile accumulate -> acc is 8 regs (was 64), so the
// whole live set fits (~90 regs) and NOTHING spills to scratch. launch_bounds
// (256,2) leaves the allocator slack; occupancy is LDS-bound at 3 blocks/CU.
// ---------------------------------------------------------------------------
__global__ __launch_bounds__(256, 2) void DensityAwareFeatureAggregator_main(
    const float4* __restrict__ pts4,      // (B*N) padded
    const _Float16* __restrict__ feat16,  // (B*N,32) f16
    const int*   __restrict__ nbr,        // (B,N,32)
    const float* __restrict__ pe_w1,      // (3,64)
    const float* __restrict__ pe_b1,      // (64)
    const float* __restrict__ b1c,        // (128) fused bias
    const _Float16* __restrict__ gB1,     // W1c frags (24 tiles)
    const _Float16* __restrict__ gW2,     // W2 frags (16 tiles)
    const float* __restrict__ b2g,        // (64)
    float* __restrict__ out)              // (B,N,64)
{
    __shared__ __align__(16) _Float16 sB1[24 * 512];     // 24576 B
    __shared__ __align__(16) float4   sTab[64];          //  1024 B
    __shared__ __align__(16) float4   sR[4][32];         //  2048 B
    __shared__ int                    sI[4][32];         //   512 B
    __shared__ __align__(16) _Float16 sHM[4][16 * 136];  // 17408 B
    // total 45568 B -> 3 blocks/CU, 12 waves/CU

    const int t = threadIdx.x;
    {
        const uint4* g = (const uint4*)gB1;
        uint4* d = (uint4*)sB1;
        for (int i = t; i < 1536; i += 256) d[i] = g[i];
        if (t < 64)
            sTab[t] = make_float4(pe_w1[t], pe_w1[64 + t], pe_w1[128 + t], pe_b1[t]);
    }
    __syncthreads();

    const int w = t >> 6, l = t & 63, q = l >> 4, c16 = l & 15;
    const int nb   = (blockIdx.x & 7) * 128 + (blockIdx.x >> 3);
    const int base = (nb * 4 + w) * 16;

    float bias1[8];
#pragma unroll
    for (int nt = 0; nt < 8; ++nt) bias1[nt] = b1c[nt * 16 + c16];

    const f16x8* B1f = (const f16x8*)sB1;
    _Float16* hmw = &sHM[w][0];

#pragma unroll 1
    for (int p = 0; p < 16; ++p) {
        const int m = base + p;
        const int b = m >> 14;
        const int n = m & (NN - 1);
        const int bo = b << 14;

        if (l < KK) {
            int idx = nbr[(size_t)m * KK + l];
            sI[w][l] = idx;
            float4 pc = pts4[bo + n];
            float4 pn = pts4[bo + idx];
            sR[w][l] = make_float4(pn.x - pc.x, pn.y - pc.y, pn.z - pc.z, 0.f);
        }

        // feature A-frags straight from global fp16 (MFMA A layout):
        // lanes q=0..3 with equal c16 read 4 quarters of one 64 B row.
        int i0 = sI[w][c16];
        int i1 = sI[w][16 + c16];
        f16x8 af0 = ((const f16x8*)(feat16 + ((size_t)(bo + i0)) * 32))[q];
        f16x8 af1 = ((const f16x8*)(feat16 + ((size_t)(bo + i1)) * 32))[q];

        // pe A-frags: tables broadcast from LDS (no VGPR arrays)
        float4 r0 = sR[w][c16];
        float4 r1 = sR[w][16 + c16];
        f16x8 ap10, ap20, ap11, ap21;
#pragma unroll
        for (int j = 0; j < 8; ++j) {
            float4 ta = sTab[q * 8 + j];
            float4 tb = sTab[32 + q * 8 + j];
            float v;
            v = fmaf(r0.x, ta.x, fmaf(r0.y, ta.y, fmaf(r0.z, ta.z, ta.w)));
            ap10[j] = (_Float16)fmaxf(v, 0.f);
            v = fmaf(r0.x, tb.x, fmaf(r0.y, tb.y, fmaf(r0.z, tb.z, tb.w)));
            ap20[j] = (_Float16)fmaxf(v, 0.f);
            v = fmaf(r1.x, ta.x, fmaf(r1.y, ta.y, fmaf(r1.z, ta.z, ta.w)));
            ap11[j] = (_Float16)fmaxf(v, 0.f);
            v = fmaf(r1.x, tb.x, fmaf(r1.y, tb.y, fmaf(r1.z, tb.z, tb.w)));
            ap21[j] = (_Float16)fmaxf(v, 0.f);
        }

        // Per-N-tile accumulate: 6 MFMAs into 2 f32x4, reduce, release.
#pragma unroll
        for (int nt = 0; nt < 8; ++nt) {
            f16x8 bf0 = B1f[nt * 64 + l];
            f16x8 bf1 = B1f[(8 + nt) * 64 + l];
            f16x8 bf2 = B1f[(16 + nt) * 64 + l];
            f32x4 a0, a1;
            a0[0] = a0[1] = a0[2] = a0[3] = bias1[nt];
            a1 = a0;
            a0 = __builtin_amdgcn_mfma_f32_16x16x32_f16(af0,  bf0, a0, 0, 0, 0);
            a1 = __builtin_amdgcn_mfma_f32_16x16x32_f16(af1,  bf0, a1, 0, 0, 0);
            a0 = __builtin_amdgcn_mfma_f32_16x16x32_f16(ap10, bf1, a0, 0, 0, 0);
            a1 = __builtin_amdgcn_mfma_f32_16x16x32_f16(ap11, bf1, a1, 0, 0, 0);
            a0 = __builtin_amdgcn_mfma_f32_16x16x32_f16(ap20, bf2, a0, 0, 0, 0);
            a1 = __builtin_amdgcn_mfma_f32_16x16x32_f16(ap21, bf2, a1, 0, 0, 0);

            float s = fmaxf(a0[0], 0.f) + fmaxf(a0[1], 0.f)
                    + fmaxf(a0[2], 0.f) + fmaxf(a0[3], 0.f)
                    + fmaxf(a1[0], 0.f) + fmaxf(a1[1], 0.f)
                    + fmaxf(a1[2], 0.f) + fmaxf(a1[3], 0.f);
            s += __shfl_xor(s, 16, 64);
            s += __shfl_xor(s, 32, 64);
            if (q == 0) hmw[p * 136 + nt * 16 + c16] = (_Float16)(s * 0.03125f);
        }
    }

    // epilogue: OUT(16x64) = HM(16x128) @ W2 + b2  (W2 frags from global, L2)
    const f16x8* W2f = (const f16x8*)gW2;
    f32x4 acc2[4];
#pragma unroll
    for (int nt = 0; nt < 4; ++nt) {
        f32x4 z; float bv = b2g[nt * 16 + c16];
        z[0] = z[1] = z[2] = z[3] = bv;
        acc2[nt] = z;
    }
#pragma unroll
    for (int ks = 0; ks < 4; ++ks) {
        f16x8 a2 = *(const f16x8*)&hmw[c16 * 136 + ks * 32 + q * 8];
#pragma unroll
        for (int nt = 0; nt < 4; ++nt) {
            f16x8 bf = W2f[(ks * 4 + nt) * 64 + l];
            acc2[nt] = __builtin_amdgcn_mfma_f32_16x16x32_f16(a2, bf, acc2[nt], 0, 0, 0);
        }
    }
#pragma unroll
    for (int nt = 0; nt < 4; ++nt)
#pragma unroll
        for (int r = 0; r < 4; ++r)
            out[(size_t)(base + q * 4 + r) * OUTF + nt * 16 + c16] = acc2[nt][r];
}

// ---------------------------------------------------------------------------
extern "C" void kernel_launch(void* const* d_in, const int* in_sizes, int n_in,
                              void* d_out, int out_size, void* d_ws, size_t ws_size,
                              hipStream_t stream)
{
    const float* points   = (const float*)d_in[0];
    const float* features = (const float*)d_in[1];
    // d_in[2] density: provably unused (softmax over K identical values = 1/K)
    const int*   nbr      = (const int*)d_in[3];
    const float* pe_w1    = (const float*)d_in[4];
    const float* pe_b1    = (const float*)d_in[5];
    const float* pe_w2    = (const float*)d_in[6];
    const float* pe_b2    = (const float*)d_in[7];
    const float* mlp_w1   = (const float*)d_in[8];
    const float* mlp_b1   = (const float*)d_in[9];
    const float* mlp_w2   = (const float*)d_in[10];
    const float* mlp_b2   = (const float*)d_in[11];

    float* wsf = (float*)d_ws;
    float*    wc     = wsf;                         // 8192 f32
    float*    b1c    = wsf + 8192;                  // 128 f32
    _Float16* gB1    = (_Float16*)(wsf + 8320);     // 12288 f16
    _Float16* gW2    = (_Float16*)(wsf + 14464);    // 8192 f16
    float4*   pts4   = (float4*)(wsf + 18560);      // 65536 float4
    _Float16* feat16 = (_Float16*)(wsf + 280704);   // 2097152 f16

    prep1_kernel<<<1, 256, 0, stream>>>(pe_w2, pe_b2, mlp_w1, mlp_b1, wc, b1c);
    prep2_kernel<<<80, 256, 0, stream>>>(mlp_w1, wc, mlp_w2, gB1, gW2);
    prepF_kernel<<<2304, 256, 0, stream>>>(features, points, feat16, pts4);

    DensityAwareFeatureAggregator_main<<<1024, 256, 0, stream>>>(
        pts4, feat16, nbr, pe_w1, pe_b1, b1c, gB1, gW2, mlp_b2,
        (float*)d_out);
}

// Round 6
// 180.204 us; speedup vs baseline: 4.4879x; 1.4195x over previous
//
#include <hip/hip_runtime.h>

#define BB   4
#define NN   16384
#define KK   32
#define HID  128
#define OUTF 64

typedef _Float16 f16x8 __attribute__((ext_vector_type(8)));
typedef _Float16 f16x4 __attribute__((ext_vector_type(4)));
typedef _Float16 f16x2 __attribute__((ext_vector_type(2)));
typedef float    f32x4 __attribute__((ext_vector_type(4)));

static __device__ __forceinline__ unsigned short h2u(_Float16 h) {
    union { _Float16 h; unsigned short u; } c; c.h = h; return c.u;
}
static __device__ __forceinline__ _Float16 u2h(unsigned short u) {
    union { _Float16 h; unsigned short u; } c; c.u = u; return c.h;
}

// ---------------------------------------------------------------------------
// prep_all: ONE kernel, no inter-block deps (gB1 tiles recompute their wc
// slice inline: wc[r][n] = sum_c pe_w2[r][c]*mlp_w1[32+c][n], ~256 FMA/thr).
// blocks 0..23   : gB1 tile pack (24 tiles, 16x16x32 B-layout, verified R2-R5)
// blocks 24..39  : gW2 tile pack (16 tiles)
// blocks 40..2343: feat fp32->fp16 + points->float4
// block  2344    : b1c = mlp_b1 + pe_b2 @ W1b
// ---------------------------------------------------------------------------
__global__ __launch_bounds__(256) void prep_all(
    const float* __restrict__ pe_w2, const float* __restrict__ pe_b2,
    const float* __restrict__ mlp_w1, const float* __restrict__ mlp_b1,
    const float* __restrict__ mlp_w2,
    const float* __restrict__ features, const float* __restrict__ points,
    _Float16* __restrict__ gB1, _Float16* __restrict__ gW2,
    float* __restrict__ b1c,
    _Float16* __restrict__ feat16, float4* __restrict__ pts4)
{
    const int bid = blockIdx.x, tid = threadIdx.x;
    if (bid >= 40) {
        if (bid == 2344) {
            if (tid < HID) {
                float a = mlp_b1[tid];
#pragma unroll 16
                for (int c = 0; c < 64; ++c)
                    a = fmaf(pe_b2[c], mlp_w1[(32 + c) * HID + tid], a);
                b1c[tid] = a;
            }
            return;
        }
        int t = (bid - 40) * 256 + tid;
        if (t < BB * NN * 8) {
            float4 v = ((const float4*)features)[t];
            f16x4 h;
            h[0] = (_Float16)v.x; h[1] = (_Float16)v.y;
            h[2] = (_Float16)v.z; h[3] = (_Float16)v.w;
            *(f16x4*)(feat16 + (size_t)t * 4) = h;
        } else {
            int i = t - BB * NN * 8;
            if (i < BB * NN) {
                const float* p = points + (size_t)i * 3;
                pts4[i] = make_float4(p[0], p[1], p[2], 0.f);
            }
        }
        return;
    }
    if (bid < 24) {   // gB1: tile (ks,nt); element e: l=e>>3, j=e&7
        int ks = bid >> 3, nt = bid & 7;
        for (int e = tid; e < 512; e += 256) {
            int l = e >> 3, j = e & 7;
            int k = ks * 32 + (l >> 4) * 8 + j;
            int n = nt * 16 + (l & 15);
            float v;
            if (k < 32) {
                v = mlp_w1[k * HID + n];
            } else {
                int r = k - 32;
                v = 0.f;
#pragma unroll 16
                for (int c = 0; c < 64; ++c)
                    v = fmaf(pe_w2[r * 64 + c], mlp_w1[(32 + c) * HID + n], v);
            }
            gB1[bid * 512 + e] = (_Float16)v;
        }
    } else {          // gW2
        int tb = bid - 24;
        int ks = tb >> 2, nt = tb & 3;
        for (int e = tid; e < 512; e += 256) {
            int l = e >> 3, j = e & 7;
            int k = ks * 32 + (l >> 4) * 8 + j;
            int n = nt * 16 + (l & 15);
            gW2[tb * 512 + e] = (_Float16)mlp_w2[k * OUTF + n];
        }
    }
}

// ---------------------------------------------------------------------------
// Main: 1024 blocks x 4 waves; one wave = 16 points, processed in PAIRS:
// full-wave nbr/rel staging (no divergence), B-frags read once per 4 M-tiles
// (halves LDS b128 traffic), pe computed with packed f16x2 math (tables in
// 32 VGPRs). Per-nt accumulate-reduce keeps live regs small (no spill, R5).
// ---------------------------------------------------------------------------
__global__ __launch_bounds__(256, 2) void DensityAwareFeatureAggregator_main(
    const float4* __restrict__ pts4,      // (B*N) padded, global index
    const _Float16* __restrict__ feat16,  // (B*N,32) f16
    const int*   __restrict__ nbr,        // (B,N,32)
    const float* __restrict__ pe_w1,      // (3,64)
    const float* __restrict__ pe_b1,      // (64)
    const float* __restrict__ b1c,        // (128) fused bias
    const _Float16* __restrict__ gB1,     // W1c frags (24 tiles)
    const _Float16* __restrict__ gW2,     // W2 frags (16 tiles)
    const float* __restrict__ b2g,        // (64)
    float* __restrict__ out)              // (B,N,64)
{
    __shared__ __align__(16) _Float16 sB1[24 * 512];     // 24576 B
    __shared__ __align__(16) f16x8    sTabH[32];         //   512 B
    __shared__ __align__(16) ushort4  sRI[4][64];        //  2048 B
    __shared__ __align__(16) _Float16 sHM[4][16 * 136];  // 17408 B
    // total 44544 B -> 3 blocks/CU

    const int t = threadIdx.x;
    {
        const uint4* g = (const uint4*)gB1;
        uint4* d = (uint4*)sB1;
        for (int i = t; i < 1536; i += 256) d[i] = g[i];
    }
    if (t < 32) {   // col-pair tables: {x0,x1,y0,y1,z0,z1,b0,b1}
        int cp = t;
        f16x8 e;
        e[0] = (_Float16)pe_w1[2 * cp];       e[1] = (_Float16)pe_w1[2 * cp + 1];
        e[2] = (_Float16)pe_w1[64 + 2 * cp];  e[3] = (_Float16)pe_w1[64 + 2 * cp + 1];
        e[4] = (_Float16)pe_w1[128 + 2 * cp]; e[5] = (_Float16)pe_w1[128 + 2 * cp + 1];
        e[6] = (_Float16)pe_b1[2 * cp];       e[7] = (_Float16)pe_b1[2 * cp + 1];
        sTabH[cp] = e;
    }
    __syncthreads();

    const int w = t >> 6, l = t & 63, q = l >> 4, c16 = l & 15;
    const int nb   = (blockIdx.x & 7) * 128 + (blockIdx.x >> 3);
    const int base = (nb * 4 + w) * 16;
    const int bo   = base & ~(NN - 1);   // batch offset into flat point ids

    // pe tables -> regs: frag cols q*8..q*8+7 (tab1) and +32 (tab2)
    f16x8 tab1[4], tab2[4];
#pragma unroll
    for (int u = 0; u < 4; ++u) {
        tab1[u] = sTabH[q * 4 + u];
        tab2[u] = sTabH[16 + q * 4 + u];
    }
    float bias1[8];
#pragma unroll
    for (int nt = 0; nt < 8; ++nt) bias1[nt] = b1c[nt * 16 + c16];

    const f16x8* B1f = (const f16x8*)sB1;
    _Float16* hmw = &sHM[w][0];

#pragma unroll 1
    for (int p2 = 0; p2 < 8; ++p2) {
        const int mA = base + 2 * p2;
        // ---- full-wave staging: lanes 0-31 point A, 32-63 point B ----
        int idx = nbr[(size_t)mA * KK + l];       // 256 B coalesced, 2 points
        float4 pc = pts4[mA + (l >> 5)];          // wave-half broadcast
        float4 pn = pts4[bo + idx];
        ushort4 st;
        st.x = h2u((_Float16)(pn.x - pc.x));
        st.y = h2u((_Float16)(pn.y - pc.y));
        st.z = h2u((_Float16)(pn.z - pc.z));
        st.w = (unsigned short)idx;
        sRI[w][l] = st;
        // same-wave LDS write->read (compiler inserts lgkmcnt)
        ushort4 eA0 = sRI[w][c16];
        ushort4 eA1 = sRI[w][16 + c16];
        ushort4 eB0 = sRI[w][32 + c16];
        ushort4 eB1 = sRI[w][48 + c16];

        // ---- feature A-frags straight from fp16 global (MFMA A layout) ----
        f16x8 afA0 = ((const f16x8*)(feat16 + ((size_t)(bo + eA0.w)) * 32))[q];
        f16x8 afA1 = ((const f16x8*)(feat16 + ((size_t)(bo + eA1.w)) * 32))[q];
        f16x8 afB0 = ((const f16x8*)(feat16 + ((size_t)(bo + eB0.w)) * 32))[q];
        f16x8 afB1 = ((const f16x8*)(feat16 + ((size_t)(bo + eB1.w)) * 32))[q];

        // ---- pe A-frags, packed f16x2 math ----
        f16x8 apA10, apA20, apA11, apA21, apB10, apB20, apB11, apB21;
        {
            const ushort4 ev[4] = { eA0, eA1, eB0, eB1 };
            f16x8* o1[4] = { &apA10, &apA11, &apB10, &apB11 };
            f16x8* o2[4] = { &apA20, &apA21, &apB20, &apB21 };
#pragma unroll
            for (int s = 0; s < 4; ++s) {
                _Float16 hx = u2h(ev[s].x), hy = u2h(ev[s].y), hz = u2h(ev[s].z);
                f16x2 rx = { hx, hx }, ry = { hy, hy }, rz = { hz, hz };
                f16x8 r1, r2;
#pragma unroll
                for (int u = 0; u < 4; ++u) {
                    f16x8 tA = tab1[u], tB = tab2[u];
                    f16x2 v1 = (f16x2){ tA[6], tA[7] };
                    v1 += (f16x2){ tA[0], tA[1] } * rx;
                    v1 += (f16x2){ tA[2], tA[3] } * ry;
                    v1 += (f16x2){ tA[4], tA[5] } * rz;
                    f16x2 v2 = (f16x2){ tB[6], tB[7] };
                    v2 += (f16x2){ tB[0], tB[1] } * rx;
                    v2 += (f16x2){ tB[2], tB[3] } * ry;
                    v2 += (f16x2){ tB[4], tB[5] } * rz;
                    _Float16 z = (_Float16)0.f;
                    r1[2*u]   = v1[0] > z ? v1[0] : z;
                    r1[2*u+1] = v1[1] > z ? v1[1] : z;
                    r2[2*u]   = v2[0] > z ? v2[0] : z;
                    r2[2*u+1] = v2[1] > z ? v2[1] : z;
                }
                *o1[s] = r1; *o2[s] = r2;
            }
        }

        // ---- per-N-tile: 3 shared B-frags, 12 MFMAs (4 M-tiles), reduce ----
#pragma unroll 2
        for (int nt = 0; nt < 8; ++nt) {
            f16x8 bf0 = B1f[nt * 64 + l];
            f16x8 bf1 = B1f[(8 + nt) * 64 + l];
            f16x8 bf2 = B1f[(16 + nt) * 64 + l];
            f32x4 aA0, aA1, aB0, aB1;
            aA0[0] = aA0[1] = aA0[2] = aA0[3] = bias1[nt];
            aA1 = aA0; aB0 = aA0; aB1 = aA0;
            aA0 = __builtin_amdgcn_mfma_f32_16x16x32_f16(afA0,  bf0, aA0, 0, 0, 0);
            aA1 = __builtin_amdgcn_mfma_f32_16x16x32_f16(afA1,  bf0, aA1, 0, 0, 0);
            aB0 = __builtin_amdgcn_mfma_f32_16x16x32_f16(afB0,  bf0, aB0, 0, 0, 0);
            aB1 = __builtin_amdgcn_mfma_f32_16x16x32_f16(afB1,  bf0, aB1, 0, 0, 0);
            aA0 = __builtin_amdgcn_mfma_f32_16x16x32_f16(apA10, bf1, aA0, 0, 0, 0);
            aA1 = __builtin_amdgcn_mfma_f32_16x16x32_f16(apA11, bf1, aA1, 0, 0, 0);
            aB0 = __builtin_amdgcn_mfma_f32_16x16x32_f16(apB10, bf1, aB0, 0, 0, 0);
            aB1 = __builtin_amdgcn_mfma_f32_16x16x32_f16(apB11, bf1, aB1, 0, 0, 0);
            aA0 = __builtin_amdgcn_mfma_f32_16x16x32_f16(apA20, bf2, aA0, 0, 0, 0);
            aA1 = __builtin_amdgcn_mfma_f32_16x16x32_f16(apA21, bf2, aA1, 0, 0, 0);
            aB0 = __builtin_amdgcn_mfma_f32_16x16x32_f16(apB20, bf2, aB0, 0, 0, 0);
            aB1 = __builtin_amdgcn_mfma_f32_16x16x32_f16(apB21, bf2, aB1, 0, 0, 0);

            float sA = fmaxf(aA0[0], 0.f) + fmaxf(aA0[1], 0.f)
                     + fmaxf(aA0[2], 0.f) + fmaxf(aA0[3], 0.f)
                     + fmaxf(aA1[0], 0.f) + fmaxf(aA1[1], 0.f)
                     + fmaxf(aA1[2], 0.f) + fmaxf(aA1[3], 0.f);
            float sB = fmaxf(aB0[0], 0.f) + fmaxf(aB0[1], 0.f)
                     + fmaxf(aB0[2], 0.f) + fmaxf(aB0[3], 0.f)
                     + fmaxf(aB1[0], 0.f) + fmaxf(aB1[1], 0.f)
                     + fmaxf(aB1[2], 0.f) + fmaxf(aB1[3], 0.f);
            sA += __shfl_xor(sA, 16, 64);
            sA += __shfl_xor(sA, 32, 64);
            sB += __shfl_xor(sB, 16, 64);
            sB += __shfl_xor(sB, 32, 64);
            if (q == 0) {
                hmw[(2 * p2) * 136 + nt * 16 + c16]     = (_Float16)(sA * 0.03125f);
                hmw[(2 * p2 + 1) * 136 + nt * 16 + c16] = (_Float16)(sB * 0.03125f);
            }
        }
    }

    // ---- epilogue: OUT(16x64) = HM(16x128) @ W2 + b2 (verified R2-R5) ----
    const f16x8* W2f = (const f16x8*)gW2;
    f32x4 acc2[4];
#pragma unroll
    for (int nt = 0; nt < 4; ++nt) {
        f32x4 z; float bv = b2g[nt * 16 + c16];
        z[0] = z[1] = z[2] = z[3] = bv;
        acc2[nt] = z;
    }
#pragma unroll
    for (int ks = 0; ks < 4; ++ks) {
        f16x8 a2 = *(const f16x8*)&hmw[c16 * 136 + ks * 32 + q * 8];
#pragma unroll
        for (int nt = 0; nt < 4; ++nt) {
            f16x8 bf = W2f[(ks * 4 + nt) * 64 + l];
            acc2[nt] = __builtin_amdgcn_mfma_f32_16x16x32_f16(a2, bf, acc2[nt], 0, 0, 0);
        }
    }
#pragma unroll
    for (int nt = 0; nt < 4; ++nt)
#pragma unroll
        for (int r = 0; r < 4; ++r)
            out[(size_t)(base + q * 4 + r) * OUTF + nt * 16 + c16] = acc2[nt][r];
}

// ---------------------------------------------------------------------------
extern "C" void kernel_launch(void* const* d_in, const int* in_sizes, int n_in,
                              void* d_out, int out_size, void* d_ws, size_t ws_size,
                              hipStream_t stream)
{
    const float* points   = (const float*)d_in[0];
    const float* features = (const float*)d_in[1];
    // d_in[2] density: provably unused (softmax over K identical values = 1/K)
    const int*   nbr      = (const int*)d_in[3];
    const float* pe_w1    = (const float*)d_in[4];
    const float* pe_b1    = (const float*)d_in[5];
    const float* pe_w2    = (const float*)d_in[6];
    const float* pe_b2    = (const float*)d_in[7];
    const float* mlp_w1   = (const float*)d_in[8];
    const float* mlp_b1   = (const float*)d_in[9];
    const float* mlp_w2   = (const float*)d_in[10];
    const float* mlp_b2   = (const float*)d_in[11];

    float* wsf = (float*)d_ws;
    float*    b1c    = wsf;                         // 128 f32
    _Float16* gB1    = (_Float16*)(wsf + 128);      // 12288 f16
    _Float16* gW2    = (_Float16*)(wsf + 6272);     // 8192 f16
    float4*   pts4   = (float4*)(wsf + 10368);      // 65536 float4
    _Float16* feat16 = (_Float16*)(wsf + 272512);   // 2097152 f16

    prep_all<<<2345, 256, 0, stream>>>(
        pe_w2, pe_b2, mlp_w1, mlp_b1, mlp_w2, features, points,
        gB1, gW2, b1c, feat16, pts4);

    DensityAwareFeatureAggregator_main<<<1024, 256, 0, stream>>>(
        pts4, feat16, nbr, pe_w1, pe_b1, b1c, gB1, gW2, mlp_b2,
        (float*)d_out);
}